// Round 2
// 595.680 us; speedup vs baseline: 1.0084x; 1.0084x over previous
//
#include <hip/hip_runtime.h>
#include <hip/hip_fp16.h>

#define NB 4096
#define NT 256
#define NC 64
#define NH 16
#define NS 10
#define NTO 255
#define TC 8
#define NCHUNK (NT/TC)

__device__ __forceinline__ float fast_rcp(float x){ return __builtin_amdgcn_rcpf(x); }
__device__ __forceinline__ float fast_rsq(float x){ return __builtin_amdgcn_rsqf(x); }
__device__ __forceinline__ float fsig(float x){ return fast_rcp(1.0f + __expf(-x)); }
__device__ __forceinline__ float ftanh(float x){
    float e = __expf(2.0f*x);
    return fmaf(-2.0f, fast_rcp(e + 1.0f), 1.0f);
}

// row_ror:R within each 16-lane row: lane l receives lane (l-R)&15's value. VALU pipe, no LDS.
template<int R>
__device__ __forceinline__ float rotf(float x){
    return __int_as_float(__builtin_amdgcn_update_dpp(
        0, __float_as_int(x), 0x120 + R, 0xF, 0xF, true));
}
// butterfly sum over the 16-lane row, result broadcast to all 16 lanes
__device__ __forceinline__ float row_bcast_sum(float x){
    x += rotf<8>(x);
    x += rotf<4>(x);
    x += rotf<2>(x);
    x += rotf<1>(x);
    return x;
}
// acc + sum_k v_k * W[k][l], v distributed one element/lane, w[r] = W[(l-r)&15][l]
__device__ __forceinline__ float rotdot16(float v, const float* w, float acc){
    float a1 = 0.f;
    acc = fmaf(v,          w[0],  acc);
    a1  = fmaf(rotf<1>(v), w[1],  a1);
    acc = fmaf(rotf<2>(v), w[2],  acc);
    a1  = fmaf(rotf<3>(v), w[3],  a1);
    acc = fmaf(rotf<4>(v), w[4],  acc);
    a1  = fmaf(rotf<5>(v), w[5],  a1);
    acc = fmaf(rotf<6>(v), w[6],  acc);
    a1  = fmaf(rotf<7>(v), w[7],  a1);
    acc = fmaf(rotf<8>(v), w[8],  acc);
    a1  = fmaf(rotf<9>(v), w[9],  a1);
    acc = fmaf(rotf<10>(v),w[10], acc);
    a1  = fmaf(rotf<11>(v),w[11], a1);
    acc = fmaf(rotf<12>(v),w[12], acc);
    a1  = fmaf(rotf<13>(v),w[13], a1);
    acc = fmaf(rotf<14>(v),w[14], acc);
    a1  = fmaf(rotf<15>(v),w[15], a1);
    return acc + a1;
}

// extract half #u (0..7, compile-time) from a float4 holding 8 fp16
__device__ __forceinline__ float xw_at(float4 v, int u){
    unsigned w = (u<2) ? __float_as_uint(v.x) : (u<4) ? __float_as_uint(v.y)
               : (u<6) ? __float_as_uint(v.z) : __float_as_uint(v.w);
    unsigned hh = (u & 1) ? (w >> 16) : (w & 0xffffu);
    return __half2float(__ushort_as_half((unsigned short)hh));
}

// ===================== K1: xw = LN(cov) @ (gamma-folded wx) + (beta@wx + rnn_b) =====================
// One wave per batch (4096 waves, 16/CU). Lane = g*16+l: g = t-subindex (4 t/iter), l = element-quarter.
// Zero LDS: stats via DPP reduce, dot via DPP rotation-systolic. Output fp16 ws[b][l][t].
__global__ __launch_bounds__(256, 4) void xw_kernel(
    const float* __restrict__ cov, const float* __restrict__ lng,
    const float* __restrict__ lnb, const float* __restrict__ wx,
    const float* __restrict__ rnb, __half* __restrict__ xws)
{
    const int wid  = threadIdx.x >> 6;
    const int lane = threadIdx.x & 63;
    const int g = lane >> 4, l = lane & 15;
    const int b = (blockIdx.x << 2) + wid;

    // rotated gamma-folded weights: gwr[4r+j] = lng[c]*wx[c][l], c = 4*((l-r)&15)+j
    float gwr[64];
    #pragma unroll
    for (int r = 0; r < 16; ++r) {
        int c0 = 4 * ((l - r) & 15);
        #pragma unroll
        for (int j = 0; j < 4; ++j)
            gwr[4*r+j] = lng[c0+j] * wx[(c0+j)*NH + l];
    }
    float bwb = rnb[l];
    #pragma unroll
    for (int c = 0; c < NC; ++c) bwb = fmaf(lnb[c], wx[c*NH + l], bwb);

    const float4* gp = (const float4*)cov + (size_t)b*NT*16 + g*16 + l;  // advance 64/iter
    __half* op = xws + ((size_t)b*16 + l)*NT + g;                        // advance 4/iter

    float4 cur = gp[0];
    float4 nxt = gp[64];
    #pragma unroll 2
    for (int it = 0; it < 64; ++it) {
        float4 x = cur;
        cur = nxt;
        if (it < 62) nxt = gp[(size_t)(it+2)*64];
        // LN stats over this row's 64 elements (16 lanes x 4)
        float ss = (x.x + x.y) + (x.z + x.w);
        float sq = fmaf(x.x,x.x, fmaf(x.y,x.y, fmaf(x.z,x.z, x.w*x.w)));
        ss = row_bcast_sum(ss);
        sq = row_bcast_sum(sq);
        float mu  = ss * (1.0f/64.0f);
        float var = fmaf(-mu, mu, sq * (1.0f/64.0f));
        float rs  = fast_rsq(var + 0.001f);
        float nmu = -mu * rs;
        float x0 = fmaf(x.x, rs, nmu), x1 = fmaf(x.y, rs, nmu);
        float x2 = fmaf(x.z, rs, nmu), x3 = fmaf(x.w, rs, nmu);
        // rotation-systolic dot over all 64 elements
        float a0 = bwb, a1 = 0.f, a2 = 0.f, a3 = 0.f;
        a0 = fmaf(x0, gwr[0], a0); a1 = fmaf(x1, gwr[1], a1);
        a2 = fmaf(x2, gwr[2], a2); a3 = fmaf(x3, gwr[3], a3);
#define ROTSTEP(R) { float r0=rotf<R>(x0), r1=rotf<R>(x1), r2=rotf<R>(x2), r3=rotf<R>(x3); \
        a0=fmaf(r0,gwr[4*R+0],a0); a1=fmaf(r1,gwr[4*R+1],a1); \
        a2=fmaf(r2,gwr[4*R+2],a2); a3=fmaf(r3,gwr[4*R+3],a3); }
        ROTSTEP(1)  ROTSTEP(2)  ROTSTEP(3)  ROTSTEP(4)  ROTSTEP(5)
        ROTSTEP(6)  ROTSTEP(7)  ROTSTEP(8)  ROTSTEP(9)  ROTSTEP(10)
        ROTSTEP(11) ROTSTEP(12) ROTSTEP(13) ROTSTEP(14) ROTSTEP(15)
#undef ROTSTEP
        float xw = (a0+a1)+(a2+a3);
        op[it*4] = __float2half(xw);
    }
}

// ===================== K2: software-pipelined scans =====================
// 1024 blocks x 1 wave; lane = g*16+l, g = batch-in-wave, l = hidden index.
// Chunked over time (TC=8). Per chunk iteration, ONE basic block contains:
//   ph1: sequential RNN for chunk k+1 (serial ~55cy/step chain)
//   ph2: driver MLP for chunk k  -- 8 INDEPENDENT timesteps (ILP hides latency)
//   ph4: cash-budget scan for chunk k (thin recurrence, LDS reads hoistable)
// The scheduler interleaves ph2/ph4 issue into ph1's stall slots.
__global__ __launch_bounds__(64, 1) void scan_kernel(
    const float* __restrict__ states, const __half* __restrict__ xws,
    const float* __restrict__ wh,     const float* __restrict__ d1w,
    const float* __restrict__ d1b,    const float* __restrict__ d2w,
    const float* __restrict__ d2b,    float* __restrict__ out)
{
    const int lane = threadIdx.x;
    const int g = lane >> 4, l = lane & 15;
    const int b = (blockIdx.x << 2) + g;

    __shared__ __align__(16) float db[2*TC*64];   // double-buffered act broadcast, 4 KB

    // rotated weight columns: w[r] = W[(l-r)&15][l]
    float whr[NH], d1r[NH], d2r[NH];
    #pragma unroll
    for (int r = 0; r < NH; ++r) {
        int src = (l - r) & 15;
        whr[r] = wh[src*NH + l];
        d1r[r] = d1w[src*NH + l];
        d2r[r] = d2w[src*NH + l];
    }
    const float d1bl = d1b[l], d2bl = d2b[l];
    // per-lane driver activation: act = A*sigmoid(B*x) + C  (lane0: 0.2*tanh via sig)
    const float Aa = (l==0)?0.4f:(l==2)?0.5f:(l==3)?0.1f:(l==4)?0.2f:(l==8)?0.35f:(l==9)?0.1f:1.0f;
    const float Ba = (l==0)?2.0f:1.0f;
    const float Ca = (l==0)?-0.2f:0.0f;

    float s0,s1,s2,s3,s4,s5,s6,s7,s8,s9;
    { const float* sp = states + (size_t)b*NT*NS;
      s0=sp[0];s1=sp[1];s2=sp[2];s3=sp[3];s4=sp[4];
      s5=sp[5];s6=sp[6];s7=sp[7];s8=sp[8];s9=sp[9]; }

    float* spo = out + (size_t)b*NTO*NS + l;
    float* ipo = out + (size_t)NB*NTO*NS + (size_t)b*NTO*7 + l;

    // per-lane xw time-series: 8 fp16 (one chunk) per float4
    const float4* xp = (const float4*)(xws + ((size_t)b*16 + l)*NT);
    float4 xcur = xp[0];
    float4 xnxt = xp[1];

    float h = 0.f;
    float hA[TC], hB[TC];

#define PH1(DST) \
    _Pragma("unroll") \
    for (int u = 0; u < TC; ++u) { h = ftanh(rotdot16(h, whr, xw_at(xcur,u))); DST[u] = h; }

#define PH2(DBK) \
    _Pragma("unroll") \
    for (int u = 0; u < TC; ++u) { \
        float t1  = ftanh(rotdot16(hA[u], d1r, d1bl)); \
        float dv  = rotdot16(t1, d2r, d2bl); \
        (DBK)[u*64 + lane] = fmaf(Aa, fsig(Ba*dv), Ca); \
    }

#define BUDGET(DBK, U) do { \
    float4 w0 = *((const float4*)((DBK) + (U)*64 + g*16)); \
    float4 w1 = *((const float4*)((DBK) + (U)*64 + g*16 + 4)); \
    float2 w2 = *((const float2*)((DBK) + (U)*64 + g*16 + 8)); \
    float rev   = fmaf(s0, w0.x, s0); \
    float cogs  = w0.y * rev; \
    float opex  = w0.z * rev; \
    float dep   = w0.w * s4; \
    float inte  = w2.y * s6; \
    float ebt   = (((rev - cogs) - opex) - dep) - inte; \
    float tax   = w2.x * fmaxf(ebt, 0.0f); \
    float ni    = ebt - tax; \
    float arn   = w1.y * rev; \
    float invn  = w1.z * cogs; \
    float apn   = w1.w * cogs; \
    float capex = w1.x * rev; \
    float ppen  = (s4 + capex) - dep; \
    float cashn = (((((s1 + ni) + dep) - capex) - (arn - s2)) - (invn - s3)) + (apn - s5); \
    float ren   = s8 + ni; \
    s0=rev; s1=cashn; s2=arn; s3=invn; s4=ppen; s5=apn; s8=ren; \
    float sv = (l==0)?rev:(l==1)?cashn:(l==2)?arn:(l==3)?invn:(l==4)?ppen: \
               (l==5)?apn:(l==6)?s6:(l==7)?s7:(l==8)?ren:s9; \
    float iv = (l==0)?rev:(l==1)?cogs:(l==2)?opex:(l==3)?dep:(l==4)?inte:(l==5)?tax:ni; \
    if (l < NS) *spo = sv; \
    if (l < 7)  *ipo = iv; \
    spo += NS; ipo += 7; \
} while(0)

    // ---- prologue: ph1 chunk0 ----
    PH1(hA)
    xcur = xnxt;
    xnxt = xp[2];

    // ---- peeled chunk 0 (skips t=0 driver step) + ph1 chunk1 ----
    {
        PH1(hB)
        float* dbk = db;                       // buffer 0
        PH2(dbk)
        #pragma unroll
        for (int u = 1; u < TC; ++u) BUDGET(dbk, u);
        #pragma unroll
        for (int u = 0; u < TC; ++u) hA[u] = hB[u];
        xcur = xnxt;
    }

    // ---- main pipelined loop: chunks 1..30 in hA, ph1 computes chunk k+1 ----
    #pragma unroll 1
    for (int k = 1; k < NCHUNK-1; ++k) {
        xnxt = xp[(k+2 < NCHUNK) ? (k+2) : (NCHUNK-1)];
        PH1(hB)
        float* dbk = db + (k & 1)*(TC*64);
        PH2(dbk)
        #pragma unroll
        for (int u = 0; u < TC; ++u) BUDGET(dbk, u);
        #pragma unroll
        for (int u = 0; u < TC; ++u) hA[u] = hB[u];
        xcur = xnxt;
    }

    // ---- epilogue: chunk 31 (no further ph1) ----
    {
        float* dbk = db + ((NCHUNK-1) & 1)*(TC*64);
        PH2(dbk)
        #pragma unroll
        for (int u = 0; u < TC; ++u) BUDGET(dbk, u);
    }

#undef PH1
#undef PH2
#undef BUDGET
}

extern "C" void kernel_launch(void* const* d_in, const int* in_sizes, int n_in,
                              void* d_out, int out_size, void* d_ws, size_t ws_size,
                              hipStream_t stream) {
    (void)in_sizes; (void)n_in; (void)ws_size; (void)out_size;
    __half* xws = (__half*)d_ws;   // 4096*16*256 fp16 = 33.5 MB
    xw_kernel<<<NB/4, 256, 0, stream>>>(
        (const float*)d_in[1],  // covariates_seq
        (const float*)d_in[2],  // ln_gamma
        (const float*)d_in[3],  // ln_beta
        (const float*)d_in[4],  // rnn_wx
        (const float*)d_in[6],  // rnn_b
        xws);
    scan_kernel<<<NB/4, 64, 0, stream>>>(
        (const float*)d_in[0],  // states_seq
        xws,
        (const float*)d_in[5],  // rnn_wh
        (const float*)d_in[7],  // d1_w
        (const float*)d_in[8],  // d1_b
        (const float*)d_in[9],  // d2_w
        (const float*)d_in[10], // d2_b
        (float*)d_out);
}